// Round 23
// baseline (83.895 us; speedup 1.0000x reference)
//
#include <hip/hip_runtime.h>

using short8 = __attribute__((ext_vector_type(8))) short;
using f32x4  = __attribute__((ext_vector_type(4))) float;
using f32x16 = __attribute__((ext_vector_type(16))) float;

__device__ __forceinline__ unsigned short f2bf(float f) {
  unsigned u = __float_as_uint(f);
  u += 0x7fffu + ((u >> 16) & 1u);
  return (unsigned short)(u >> 16);
}

// ---------------- pack W f32 [384k][384c] -> MFMA B-frag blobs wtp[kk 12][ct16 24][lane 64][8] ----------------
__global__ __launch_bounds__(256) void pack_w_kernel(const float* __restrict__ W,
                                                     unsigned short* __restrict__ wtp) {
  const int f = blockIdx.x * 4 + (threadIdx.x >> 6);   // 0..287
  const int l = threadIdx.x & 63;
  const int kk = f / 24, ct = f % 24;
  const int il = l & 15, kg = l >> 4;
  const float* src = W + (size_t)(kk * 32 + kg * 8) * 384 + ct * 16 + il;
  short8 v;
#pragma unroll
  for (int e = 0; e < 8; ++e) v[e] = (short)f2bf(src[(size_t)e * 384]);
  *reinterpret_cast<short8*>((char*)wtp + ((size_t)f << 10) + l * 16) = v;
}

// ---------------- adj int32 -> bitmask [2048][64] words (+ zero f1/f2/dsum) ----------------
__global__ __launch_bounds__(256) void adjmask_kernel(const int* __restrict__ adj,
                                                      unsigned* __restrict__ adjm,
                                                      float* __restrict__ f12,
                                                      float* __restrict__ dsum) {
  if (blockIdx.x < 64) f12[blockIdx.x * 256 + threadIdx.x] = 0.f;           // f1+f2 (16384)
  else if (blockIdx.x < 96) dsum[(blockIdx.x - 64) * 256 + threadIdx.x] = 0.f;  // dsum (8192)
  const int wv = (blockIdx.x << 2) + (threadIdx.x >> 6);
  const int lane = threadIdx.x & 63;
  const int row = wv >> 5, j0 = (wv & 31) << 6;
  unsigned long long mask = __ballot(adj[(size_t)row * 2048 + j0 + lane] > 0);
  if (lane == 0) {
    adjm[row * 64 + (j0 >> 5)]     = (unsigned)mask;
    adjm[row * 64 + (j0 >> 5) + 1] = (unsigned)(mask >> 32);
  }
}

// ---------------- Kernel B: fused conv + Wh GEMM + pack + f1/f2 (16-row, col-split) ----------------
__global__ __launch_bounds__(256) void gemm_wh5_kernel(const float* __restrict__ x,
                                                       const float* __restrict__ cw,
                                                       const float* __restrict__ cb,
                                                       const unsigned short* __restrict__ wtp,
                                                       const float* __restrict__ a,
                                                       unsigned short* __restrict__ whp,
                                                       float* __restrict__ f1,
                                                       float* __restrict__ f2) {
  __shared__ __align__(16) char lds[24768 + 6400 + 1792];
  float* xin = (float*)lds;                                   // [12][516], 514 used
  unsigned short* atile = (unsigned short*)lds;               // [16][392]
  unsigned short* wtile = (unsigned short*)(lds + 24768);     // [16][200]
  float* cws = (float*)(lds + 24768 + 6400);                  // 432
  float* cbs = cws + 432;                                     // 12

  const int tid = threadIdx.x;
  const int rb = blockIdx.x;
  const int b = rb >> 8;
  const int jg2 = (rb >> 1) & 127;
  const int ch2 = rb & 1;
  const int r0 = ((b << 7) + jg2) << 4;
  const int w = tid >> 6, lane = tid & 63;
  const int il = lane & 15, kg = lane >> 4;

  for (int i = tid; i < 432; i += 256) cws[i] = cw[i];
  if (tid < 12) cbs[tid] = cb[tid];
  const float* xb = x + (size_t)b * 2048 * 12 * 32;
#pragma unroll
  for (int t = 0; t < 12; ++t) {
    for (int i = tid; i < 514; i += 256) {
      const int gp = jg2 * 512 + i - 1;
      float v = 0.f;
      if ((unsigned)gp < 65536u) v = xb[((size_t)(gp >> 5) * 12 + t) * 32 + (gp & 31)];
      xin[t * 516 + i] = v;
    }
  }
  __syncthreads();

  const int ploc = tid * 2;
  float accv0[12], accv1[12];
#pragma unroll
  for (int to = 0; to < 12; ++to) { accv0[to] = cbs[to]; accv1[to] = cbs[to]; }
#pragma unroll
  for (int ti = 0; ti < 12; ++ti) {
    const float x0 = xin[ti * 516 + ploc];
    const float x1 = xin[ti * 516 + ploc + 1];
    const float x2 = xin[ti * 516 + ploc + 2];
    const float x3 = xin[ti * 516 + ploc + 3];
#pragma unroll
    for (int to = 0; to < 12; ++to) {
      const float* wp = &cws[(to * 12 + ti) * 3];
      const float w0 = wp[0], w1 = wp[1], w2 = wp[2];
      accv0[to] += x0 * w0 + x1 * w1 + x2 * w2;
      accv1[to] += x1 * w0 + x2 * w1 + x3 * w2;
    }
  }
  __syncthreads();

  {
    const int row = ploc >> 5, f = ploc & 31;
    unsigned* ap32 = (unsigned*)(atile + row * 392 + f);
#pragma unroll
    for (int to = 0; to < 12; ++to) {
      const unsigned lo = f2bf(accv0[to]), hi = f2bf(accv1[to]);
      ap32[to * 16] = lo | (hi << 16);
    }
  }
  __syncthreads();

  f32x4 acc[3];
#pragma unroll
  for (int t = 0; t < 3; ++t) acc[t] = (f32x4){0.f, 0.f, 0.f, 0.f};
  const unsigned short* arow = atile + il * 392 + kg * 8;
  const int ct0 = ch2 * 12 + w * 3;
  const char* wb = (const char*)wtp + ((size_t)ct0 << 10) + lane * 16;

  short8 bcur[3], bnxt[3];
#pragma unroll
  for (int t = 0; t < 3; ++t)
    bcur[t] = *reinterpret_cast<const short8*>(wb + ((size_t)t << 10));
#pragma unroll
  for (int kk = 0; kk < 12; ++kk) {
    if (kk < 11) {
#pragma unroll
      for (int t = 0; t < 3; ++t)
        bnxt[t] = *reinterpret_cast<const short8*>(wb + (((size_t)(kk + 1) * 24 + t) << 10));
    }
    short8 af = *reinterpret_cast<const short8*>(arow + kk * 32);
#pragma unroll
    for (int t = 0; t < 3; ++t)
      acc[t] = __builtin_amdgcn_mfma_f32_16x16x32_bf16(af, bcur[t], acc[t], 0, 0, 0);
#pragma unroll
    for (int t = 0; t < 3; ++t) bcur[t] = bnxt[t];
  }

  float p1[4] = {0.f, 0.f, 0.f, 0.f}, p2[4] = {0.f, 0.f, 0.f, 0.f};
#pragma unroll
  for (int t = 0; t < 3; ++t) {
    const int c = (ct0 + t) * 16 + il;
    const float a1v = a[c], a2v = a[384 + c];
#pragma unroll
    for (int r = 0; r < 4; ++r) { p1[r] += acc[t][r] * a1v; p2[r] += acc[t][r] * a2v; }
  }
#pragma unroll
  for (int off = 1; off < 16; off <<= 1) {
#pragma unroll
    for (int r = 0; r < 4; ++r) { p1[r] += __shfl_xor(p1[r], off); p2[r] += __shfl_xor(p2[r], off); }
  }
  if (il == 0) {
#pragma unroll
    for (int r = 0; r < 4; ++r) {
      atomicAdd(&f1[r0 + kg * 4 + r], p1[r]);
      atomicAdd(&f2[r0 + kg * 4 + r], p2[r]);
    }
  }
#pragma unroll
  for (int t = 0; t < 3; ++t)
#pragma unroll
    for (int r = 0; r < 4; ++r)
      wtile[(kg * 4 + r) * 200 + (w * 3 + t) * 16 + il] = f2bf(acc[t][r]);
  __syncthreads();

#pragma unroll
  for (int rep = 0; rep < 2; ++rep) {
    const int flat = rep * 256 + tid;
    if (flat < 384) {
      const int ct32l = flat >> 6, l = flat & 63;
      const int l5 = l & 31, hw2 = l >> 5;
      short8 v;
#pragma unroll
      for (int e = 0; e < 8; ++e)
        v[e] = (short)wtile[(hw2 * 8 + e) * 200 + ct32l * 32 + l5];
      const int ct32g = ch2 * 6 + ct32l;
      *reinterpret_cast<short8*>((char*)whp +
          ((((size_t)b * 128 + jg2) * 12 + ct32g) << 10) + l * 16) = v;
    }
  }
}

// ---------------- per-batch max of f2 ----------------
__global__ __launch_bounds__(256) void f2max_kernel(const float* __restrict__ f2,
                                                    float* __restrict__ gmax) {
  __shared__ float wm[4];
  const int b = blockIdx.x;
  const int tid = threadIdx.x;
  float m = -3.0e38f;
  for (int i = tid; i < 2048; i += 256) m = fmaxf(m, f2[b * 2048 + i]);
#pragma unroll
  for (int off = 32; off; off >>= 1) m = fmaxf(m, __shfl_xor(m, off));
  if ((tid & 63) == 0) wm[tid >> 6] = m;
  __syncthreads();
  if (tid == 0) gmax[b] = fmaxf(fmaxf(wm[0], wm[1]), fmaxf(wm[2], wm[3]));
}

// ---------------- pgen: P matrix in A-frag layout + row denominators ----------------
// grid 2048: b = bi>>9, rg = (bi>>3)&63 (32 rows), jc = bi&7 (256 j).
// php[b][rg 64][jstep 128][lane 64][8]: lane l elem e = P[i0+(l&31)][js*16 + (l>>5)*8 + e]
__global__ __launch_bounds__(256) void pgen_kernel(const float* __restrict__ f1,
                                                   const float* __restrict__ f2,
                                                   const unsigned* __restrict__ adjm,
                                                   const float* __restrict__ gmax,
                                                   unsigned short* __restrict__ php,
                                                   float* __restrict__ dsum) {
  __shared__ float ds[32];
  const int bi = blockIdx.x;
  const int b = bi >> 9;
  const int rg = (bi >> 3) & 63;
  const int jc = bi & 7;
  const int tid = threadIdx.x;
  const int wv = tid >> 6, lane = tid & 63;
  const int l5 = lane & 31, hw = lane >> 5;
  const int hw8 = hw * 8;
  const int ig = rg * 32 + l5;
  if (tid < 32) ds[tid] = 0.f;
  __syncthreads();

  const float f1v = f1[b * 2048 + ig];
  const float gm = gmax[b];
  const float mz = f1v + gm;
  const float m  = fmaxf(mz, 0.2f * mz);
  const float Az = f1v - m;
  const float Bz = 0.2f * f1v - m;
  const float* f2b = f2 + b * 2048;
  const unsigned* adjrow = adjm + (size_t)ig * 64;
  char* phpb = (char*)php + ((((size_t)b * 64 + rg) * 128) << 10) + lane * 16;

  float dloc = 0.f;
#pragma unroll
  for (int s = 0; s < 4; ++s) {
    const int js = jc * 16 + wv * 4 + s;
    const int j0 = js * 16;
    const float* fp = f2b + j0 + hw8;
    const float4 g0 = *reinterpret_cast<const float4*>(fp);
    const float4 g1 = *reinterpret_cast<const float4*>(fp + 4);
    const unsigned word = adjrow[j0 >> 5];
    const unsigned bits = word >> ((j0 & 16) + hw8);
    const float gv[8] = {g0.x, g0.y, g0.z, g0.w, g1.x, g1.y, g1.z, g1.w};
    union { unsigned short s[8]; short8 s8; } v;
#pragma unroll
    for (int e = 0; e < 8; ++e) {
      const float z = Az + gv[e];
      const float ee = fmaxf(z, fmaf(gv[e], 0.2f, Bz));
      const float p = ((bits >> e) & 1u) ? __expf(ee) : 0.f;
      dloc += p;
      v.s[e] = (unsigned short)((__float_as_uint(p) + 0x8000u) >> 16);
    }
    *reinterpret_cast<short8*>(phpb + ((size_t)js << 10)) = v.s8;
  }
  atomicAdd(&ds[l5], dloc);
  __syncthreads();
  if (tid < 32) atomicAdd(&dsum[b * 2048 + rg * 32 + tid], ds[tid]);
}

// ---------------- Kernel E: attention v14 — pure streaming GEMM, P precomputed ----------------
// grid 768: combo = bi%12 -> b = combo&3, ch = combo>>2 (128 cols); rg = bi/12 -> 32 rows.
// 4 waves = 4 ks (512 j, 32 steps of 16 j). acc 64 regs; A+B depth-2.
__global__ __launch_bounds__(256, 3) void attn14_kernel(const unsigned short* __restrict__ php,
                                                        const unsigned short* __restrict__ whp,
                                                        const float* __restrict__ dsum,
                                                        float* __restrict__ out) {
  __shared__ float red[4][32][64];      // 32 KB
  const int bi = blockIdx.x;
  const int combo = bi % 12;
  const int b  = combo & 3;
  const int ch = combo >> 2;            // 0..2
  const int rg = bi / 12;
  const int i0 = rg << 5;
  const int tid = threadIdx.x;
  const int ks = tid >> 6;
  const int lane = tid & 63;
  const int l5 = lane & 31, hw = lane >> 5;

  const char* abase = (const char*)php +
      ((((size_t)b * 64 + rg) * 128 + ks * 32) << 10) + lane * 16;
  const char* pbase = (const char*)whp +
      ((((size_t)b * 128 + ks * 32) * 12 + ch * 4) << 10) + lane * 16;

  const f32x16 zero16 = {0.f,0.f,0.f,0.f,0.f,0.f,0.f,0.f,0.f,0.f,0.f,0.f,0.f,0.f,0.f,0.f};
  f32x16 acc[4];
#pragma unroll
  for (int t = 0; t < 4; ++t) acc[t] = zero16;

  short8 aA, aB, bA[4], bB[4];

#define LOADAB(AS, BR, KK)                                                              \
  { AS = *reinterpret_cast<const short8*>(abase + ((size_t)(KK) << 10));                \
    _Pragma("unroll")                                                                   \
    for (int tt = 0; tt < 4; ++tt)                                                      \
      BR[tt] = *reinterpret_cast<const short8*>(pbase + (size_t)(KK) * 12288 +          \
                                                (size_t)tt * 1024); }

  LOADAB(aA, bA, 0) LOADAB(aB, bB, 1)
  for (int t = 0; t < 16; ++t) {
#pragma unroll
    for (int tt = 0; tt < 4; ++tt)
      acc[tt] = __builtin_amdgcn_mfma_f32_32x32x16_bf16(aA, bA[tt], acc[tt], 0, 0, 0);
    if (t < 15) LOADAB(aA, bA, 2 * t + 2)
#pragma unroll
    for (int tt = 0; tt < 4; ++tt)
      acc[tt] = __builtin_amdgcn_mfma_f32_32x32x16_bf16(aB, bB[tt], acc[tt], 0, 0, 0);
    if (t < 15) LOADAB(aB, bB, 2 * t + 3)
  }
#undef LOADAB

  // ---- epilogue: combine 4 ks accumulators via LDS, normalize by dsum, elu, store ----
  const float* dsb = dsum + b * 2048 + i0;
#pragma unroll
  for (int r = 0; r < 2; ++r) {
#pragma unroll
    for (int tt = 0; tt < 2; ++tt) {
#pragma unroll
      for (int q = 0; q < 16; ++q) {
        const int row = (q & 3) + 8 * (q >> 2) + 4 * hw;
        red[ks][row][tt * 32 + l5] = acc[r * 2 + tt][q];
      }
    }
    __syncthreads();
    const size_t ob = ((size_t)b * 2048 + i0) * 384 + ch * 128 + r * 64;
#pragma unroll
    for (int p = 0; p < 8; ++p) {
      const int idx = p * 256 + tid;
      const int row = idx >> 6;
      const int c = idx & 63;
      float v = red[0][row][c] + red[1][row][c] + red[2][row][c] + red[3][row][c];
      v /= dsb[row];
      v = v > 0.f ? v : expm1f(v);
      out[ob + (size_t)row * 384 + c] = v;
    }
    __syncthreads();
  }
}

extern "C" void kernel_launch(void* const* d_in, const int* in_sizes, int n_in,
                              void* d_out, int out_size, void* d_ws, size_t ws_size,
                              hipStream_t stream) {
  const float* x  = (const float*)d_in[0];
  const int* adj  = (const int*)d_in[1];
  const float* W  = (const float*)d_in[2];
  const float* a  = (const float*)d_in[3];
  const float* cw = (const float*)d_in[4];
  const float* cb = (const float*)d_in[5];
  float* out = (float*)d_out;

  char* ws = (char*)d_ws;
  unsigned short* wtp = (unsigned short*)ws; ws += (size_t)147456 * 2;    // packed W B-frags
  unsigned short* whp = (unsigned short*)ws; ws += (size_t)3145728 * 2;   // packed Wh B-frags
  unsigned short* php = (unsigned short*)ws; ws += (size_t)16777216 * 2;  // packed P A-frags (33.5 MB)
  float* f1           = (float*)ws;          ws += (size_t)8192 * 4;
  float* f2           = (float*)ws;          ws += (size_t)8192 * 4;
  float* dsum         = (float*)ws;          ws += (size_t)8192 * 4;
  unsigned* adjm      = (unsigned*)ws;       ws += (size_t)2048 * 64 * 4;
  float* gmax         = (float*)ws;          ws += 64;

  pack_w_kernel<<<dim3(72), 256, 0, stream>>>(W, wtp);
  adjmask_kernel<<<dim3(16384), 256, 0, stream>>>(adj, adjm, f1, dsum);
  gemm_wh5_kernel<<<dim3(1024), 256, 0, stream>>>(x, cw, cb, wtp, a, whp, f1, f2);
  f2max_kernel<<<dim3(4), 256, 0, stream>>>(f2, gmax);
  pgen_kernel<<<dim3(2048), 256, 0, stream>>>(f1, f2, adjm, gmax, php, dsum);
  attn14_kernel<<<dim3(768), 256, 0, stream>>>(php, whp, dsum, out);
}